// Round 1
// 134.699 us; speedup vs baseline: 1.2625x; 1.2625x over previous
//
#include <hip/hip_runtime.h>
#include <hip/hip_bf16.h>

// R6: single-product bf16 MFMA (zHi x eHi only), wave-owns-codes layout,
// en2 / E-fragments precomputed once in vq_prep, loss accumulator zeroed in
// prep (memset dispatch dropped).
//
// Numerics: emb ~ U(+-1/512) is tiny, so score err = -2*Sum(dz*e + z*de) has
// std ~6e-5 (every rounding error multiplies a ~1e-3 partner). EPS widened
// 2e-4 -> 1e-3 (>=12 sigma of the pairwise error diff); exact fp32 reference
// rescore of band candidates + u64 (dist_bits<<32|idx) atomicMin strict-<
// ascending-k tie-break unchanged from the validated R5 scheme.
constexpr int NELEM = 8388608;            // 32*64*64*64
constexpr int ROWS  = 64;                 // rows per block
constexpr int NBLK  = 131072 / ROWS;      // 2048
constexpr int ZS    = 68;                 // z tile stride (dwords)
constexpr float EPS = 1e-3f;              // single-product band (see header)
constexpr int QCAP  = 1024;               // candidate queue (~110 expected)

typedef short bf16x8 __attribute__((ext_vector_type(8)));
typedef float v4f    __attribute__((ext_vector_type(4)));

// Precomputed E fragments, hi-only, scale -2: [ct][kc][lane] -> 8 bf16, 64 KB.
__device__ bf16x8 g_efrag[32][2][64];
// Precomputed ||e||^2 in exact reference quad-accumulator order.
__device__ float  g_en2[512];

__device__ inline bf16x8 cvt_hi8(const float* __restrict__ s, float scale) {
    bf16x8 h;
#pragma unroll
    for (int j = 0; j < 8; ++j) {
        __hip_bfloat16 b = __float2bfloat16(scale * s[j]);
        h[j] = (short)__bfloat16_as_ushort(b);
    }
    return h;
}

// 17 blocks: 0..15 build E fragments (256 entries each), 16 builds en2 + out[0]=0.
__global__ void __launch_bounds__(256) vq_prep(const float* __restrict__ emb,
                                               float* __restrict__ out) {
    const int b = blockIdx.x;
    if (b < 16) {
        const int id   = b * 256 + threadIdx.x;   // (ct,kc,lane), 4096 total
        const int lane = id & 63;
        const int kc   = (id >> 6) & 1;
        const int ct   = id >> 7;
        const float* src = emb + (size_t)(ct * 16 + (lane & 15)) * 64
                               + kc * 32 + (lane >> 4) * 8;
        g_efrag[ct][kc][lane] = cvt_hi8(src, -2.0f);
    } else {
#pragma unroll
        for (int c = 0; c < 2; ++c) {
            const int k = threadIdx.x + c * 256;
            const float4* e4 = (const float4*)(emb + (size_t)k * 64);
            float a = 0.f, bq = 0.f, cc = 0.f, d = 0.f;
#pragma unroll
            for (int i = 0; i < 16; ++i) {
                float4 v = e4[i];
                a += v.x * v.x; bq += v.y * v.y; cc += v.z * v.z; d += v.w * v.w;
            }
            g_en2[k] = (a + bq) + (cc + d);
        }
        if (threadIdx.x == 0) out[0] = 0.f;
    }
}

// Block = 256 threads = 4 waves, 64 rows x 512 codes. Wave w owns codes
// [128w,128w+128) for ALL 64 rows: acc[rg][ct] (rg = 16-row group, ct = local
// 16-code tile) stays in registers (128 VGPRs). MFMA 16x16x32: A=-2E (m=code),
// B=Z (n=row), C: col=lane&15 (row), row=quad*4+reg (code) [m89 layout,
// R5-validated]. Per-wave E-slice read = 16 KB (was 128 KB/wave).
__global__ __launch_bounds__(256) __attribute__((amdgpu_waves_per_eu(2, 2)))
void vq_main(const float* __restrict__ z,
             const float* __restrict__ emb,
             float* __restrict__ out) {
    __shared__ float s_z[ROWS * ZS];          // 17.4 KB fp32 z tile
    __shared__ float s_en2[512];
    __shared__ float s_zn2[ROWS];
    __shared__ unsigned long long s_key[ROWS];
    __shared__ float s_wmin[ROWS][4];         // per-wave row mins
    __shared__ float s_thr[ROWS];             // global row min + EPS
    __shared__ unsigned s_q[QCAP];            // (row<<16)|code
    __shared__ int s_qn;
    __shared__ float s_lpart[4];

    const int tid  = threadIdx.x;
    const int lane = tid & 63;
    const int wid  = __builtin_amdgcn_readfirstlane(tid >> 6);
    const int mcol = lane & 15;
    const int quad = lane >> 4;

    // ---- stage z tile (coalesced), load en2, init queue/keys ----
    {
        const int row = tid >> 2, seg = tid & 3;
        const float4* gp = (const float4*)(z + ((size_t)blockIdx.x * ROWS + row) * 64 + seg * 16);
#pragma unroll
        for (int i = 0; i < 4; ++i)
            *(float4*)&s_z[row * ZS + seg * 16 + i * 4] = gp[i];
    }
    s_en2[tid]       = g_en2[tid];
    s_en2[tid + 256] = g_en2[tid + 256];
    if (tid < ROWS) s_key[tid] = ~0ULL;
    if (tid == 0) s_qn = 0;
    __syncthreads();

    // ---- exact zn2 per row (reference order), wave 0 only ----
    if (tid < ROWS) {
        const float* zr = &s_z[tid * ZS];
        float a = 0.f, b = 0.f, c = 0.f, d = 0.f;
#pragma unroll
        for (int i = 0; i < 16; ++i) {
            a += zr[4*i]   * zr[4*i];   b += zr[4*i+1] * zr[4*i+1];
            c += zr[4*i+2] * zr[4*i+2]; d += zr[4*i+3] * zr[4*i+3];
        }
        s_zn2[tid] = (a + b) + (c + d);
    }

    // ---- Z fragments (hi only) for all 4 row-groups ----
    bf16x8 zf[4][2];
#pragma unroll
    for (int rg = 0; rg < 4; ++rg) {
        zf[rg][0] = cvt_hi8(&s_z[(rg * 16 + mcol) * ZS +  0 + quad * 8], 1.0f);
        zf[rg][1] = cvt_hi8(&s_z[(rg * 16 + mcol) * ZS + 32 + quad * 8], 1.0f);
    }

    // ---- main loop: 8 code-tiles x 4 row-groups, scores retained ----
    v4f acc[4][8];
    float lmin[4];
#pragma unroll
    for (int rg = 0; rg < 4; ++rg) lmin[rg] = 3.402823466e38f;
#pragma unroll
    for (int ct = 0; ct < 8; ++ct) {
        const int gct = wid * 8 + ct;
        bf16x8 e0 = g_efrag[gct][0][lane];
        bf16x8 e1 = g_efrag[gct][1][lane];
        v4f base = *(const v4f*)&s_en2[gct * 16 + quad * 4];  // broadcast read
#pragma unroll
        for (int rg = 0; rg < 4; ++rg) {
            v4f a = base;
            a = __builtin_amdgcn_mfma_f32_16x16x32_bf16(e0, zf[rg][0], a, 0, 0, 0);
            a = __builtin_amdgcn_mfma_f32_16x16x32_bf16(e1, zf[rg][1], a, 0, 0, 0);
            acc[rg][ct] = a;
            lmin[rg] = fminf(lmin[rg], fminf(fminf(a.x, a.y), fminf(a.z, a.w)));
        }
    }

    // ---- per-row min: reduce across quads, then across waves via LDS ----
#pragma unroll
    for (int rg = 0; rg < 4; ++rg) {
        float m = lmin[rg];
        m = fminf(m, __shfl_xor(m, 16, 64));
        m = fminf(m, __shfl_xor(m, 32, 64));
        if (quad == 0) s_wmin[rg * 16 + mcol][wid] = m;
    }
    __syncthreads();
    if (tid < ROWS)
        s_thr[tid] = fminf(fminf(s_wmin[tid][0], s_wmin[tid][1]),
                           fminf(s_wmin[tid][2], s_wmin[tid][3])) + EPS;
    __syncthreads();

    // ---- band scan over register scores -> candidate queue ----
#pragma unroll
    for (int rg = 0; rg < 4; ++rg) {
        const int row = rg * 16 + mcol;
        const float thr = s_thr[row];
#pragma unroll
        for (int ct = 0; ct < 8; ++ct) {
            v4f a = acc[rg][ct];
            float m4 = fminf(fminf(a.x, a.y), fminf(a.z, a.w));
            if (m4 <= thr) {
#pragma unroll
                for (int r = 0; r < 4; ++r) {
                    if (a[r] <= thr) {
                        int slot = atomicAdd(&s_qn, 1);
                        if (slot < QCAP)
                            s_q[slot] = ((unsigned)row << 16) |
                                        (unsigned)(wid * 128 + ct * 16 + quad * 4 + r);
                    }
                }
            }
        }
    }
    __syncthreads();

    // ---- exact reference rescore of candidates (parallel pass) ----
    {
        const int qn = s_qn;
        for (int i = tid; i < qn && i < QCAP; i += 256) {
            const unsigned e = s_q[i];
            const int row = e >> 16, code = e & 0xFFFF;
            const float* zr = &s_z[row * ZS];
            const float* er = emb + (size_t)code * 64;
            float a = 0.f, b = 0.f, c2 = 0.f, d = 0.f;
#pragma unroll
            for (int g = 0; g < 16; ++g) {
                a  += zr[4*g]   * er[4*g];   b += zr[4*g+1] * er[4*g+1];
                c2 += zr[4*g+2] * er[4*g+2]; d += zr[4*g+3] * er[4*g+3];
            }
            float dot  = (a + b) + (c2 + d);
            float dist = (s_zn2[row] + s_en2[code]) - 2.0f * dot;  // reference expr
            unsigned long long key =
                ((unsigned long long)__float_as_uint(dist) << 32) | (unsigned)code;
            atomicMin(&s_key[row], key);
        }
    }
    __syncthreads();

    // ---- epilogue: quantized_st, indices, loss (row = tid>>2, 16 floats) ----
    const int row = tid >> 2, seg = tid & 3;
    const int widx = (int)(unsigned)(s_key[row] & 0x1FFULL);
    const float* er = emb + (size_t)widx * 64 + seg * 16;
    const float* zr = &s_z[row * ZS + seg * 16];
    float* qo = out + 1 + ((size_t)blockIdx.x * ROWS + row) * 64 + seg * 16;
    float lsum = 0.f;
#pragma unroll
    for (int j = 0; j < 16; ++j) {
        float zv = zr[j], ev = er[j];
        float q = zv + (ev - zv);    // reference STE arithmetic
        float df = q - zv; lsum += df * df;
        qo[j] = q;
    }
    if (seg == 0)
        out[1 + NELEM + blockIdx.x * ROWS + row] = (float)widx;

#pragma unroll
    for (int off = 32; off; off >>= 1) lsum += __shfl_down(lsum, off, 64);
    if (lane == 0) s_lpart[wid] = lsum;
    __syncthreads();
    if (tid == 0) {
        float p = (s_lpart[0] + s_lpart[1]) + (s_lpart[2] + s_lpart[3]);
        atomicAdd(out, p * (1.25f / 8388608.0f));   // recon + 0.25*commit
    }
}

extern "C" void kernel_launch(void* const* d_in, const int* in_sizes, int n_in,
                              void* d_out, int out_size, void* d_ws, size_t ws_size,
                              hipStream_t stream) {
    const float* z   = (const float*)d_in[0];
    const float* emb = (const float*)d_in[1];
    float* out = (float*)d_out;

    vq_prep<<<17, 256, 0, stream>>>(emb, out);   // also zeroes out[0]
    vq_main<<<NBLK, 256, 0, stream>>>(z, emb, out);
}